// Round 4
// baseline (681.120 us; speedup 1.0000x reference)
//
#include <hip/hip_runtime.h>
#include <cstdint>
#include <cstddef>

// ---------- types ----------
typedef __attribute__((ext_vector_type(8)))  __bf16 bf16x8;
typedef __attribute__((ext_vector_type(4)))  float  f32x4;
typedef __attribute__((ext_vector_type(2)))  unsigned int u32x2;

#define DI __device__ __forceinline__

// ---------- problem constants ----------
constexpr int Cdim = 768;
constexpr int C3   = 2304;
constexpr int NT   = 65;                 // tokens per window (64 + unseen)
constexpr int ROWS = 1024 * NT;          // 66560
constexpr int ROWS_PAD = ROWS + 32;
constexpr int TP   = 96;                 // padded token dim for PV (3 x K32)
constexpr int PS   = 128;                // P LDS row stride in elems
constexpr long long OUT_IMG = 16LL * 4096 * 768;  // 50331648 floats

DI float bf2f(unsigned short u) { unsigned int x = (unsigned int)u << 16; float f; __builtin_memcpy(&f, &x, 4); return f; }
DI unsigned short f2bf(float f) { unsigned int x; __builtin_memcpy(&x, &f, 4); x = x + 0x7fffu + ((x >> 16) & 1u); return (unsigned short)(x >> 16); }

DI void gload_lds16(const unsigned short* g, unsigned short* l) {
  __builtin_amdgcn_global_load_lds((__attribute__((address_space(1))) void*)g,
                                   (__attribute__((address_space(3))) void*)l, 16, 0, 0);
}

// ---------- K0: weights -> bf16, rope table ----------
__global__ void k_prep(const float* __restrict__ qkv_w, const float* __restrict__ proj_w,
                       unsigned short* __restrict__ wqb, unsigned short* __restrict__ wpb,
                       float* __restrict__ rope) {
  const int NW1 = 2304 * 768;
  const int NW2 = 768 * 768;
  int total = NW1 + NW2 + 1024;
  for (int i = blockIdx.x * blockDim.x + threadIdx.x; i < total; i += gridDim.x * blockDim.x) {
    if (i < NW1) wqb[i] = f2bf(qkv_w[i]);
    else if (i < NW1 + NW2) wpb[i - NW1] = f2bf(proj_w[i - NW1]);
    else {
      int e = i - NW1 - NW2;            // e = p*16 + j
      int p = e >> 4, j = e & 15;
      float inv = powf(100.f, -(float)j * (1.f / 16.f));
      float a = (float)p * inv;
      rope[2 * e]     = cosf(a);
      rope[2 * e + 1] = sinf(a);
    }
  }
}

// ---------- K1: window partition + unseen append -> bf16 xw [66560][768] ----------
__global__ void k_xw(const float* __restrict__ x, const float* __restrict__ unseen,
                     unsigned short* __restrict__ xw) {
  int row = blockIdx.x;
  int w = row / NT, t = row - w * NT;
  const float* src;
  if (t == 64) {
    src = unseen + (size_t)(w >> 6) * Cdim;
  } else {
    int wy = (w >> 3) & 7, wx = w & 7;
    int hw = ((wy << 3) + (t >> 3)) * 64 + (wx << 3) + (t & 7);
    src = x + ((size_t)(w >> 6) * 4096 + hw) * Cdim;
  }
  float4 v = ((const float4*)src)[threadIdx.x];
  unsigned int u0 = (unsigned)f2bf(v.x) | ((unsigned)f2bf(v.y) << 16);
  unsigned int u1 = (unsigned)f2bf(v.z) | ((unsigned)f2bf(v.w) << 16);
  ((u32x2*)(xw + (size_t)row * Cdim))[threadIdx.x] = (u32x2){u0, u1};
}

// ---------- GEMM: C[M=66560, N] = A[M,768] @ Bw[N,768]^T + bias ----------
// m201-style 8-phase schedule: 256x256 tile, BK=64, 8 waves (2Mx4N, per-wave
// 128x64), 2 LDS double-buffers (A 2x32KB + B 2x32KB = 128 KiB).
// Per phase: {ds_read subtile | stage 1 half-tile | barrier | lgkmcnt(0)+schedbar |
// setprio(1) 16 MFMA setprio(0) | barrier}. Counted vmcnt(4) once per K-tile.
// Stage slots at tile T: P0/P1 -> A halves of tile T+1 (other buffer);
// P2/P3 -> B halves of tile T+2 (current buffer; B reads drained at P1).
// Both-sides XOR-8 swizzle: chunk ^= row&7 (lane-static on each side).
template<int MODE, int NTILES>
__global__ __launch_bounds__(512, 2) void k_gemm(
    const unsigned short* __restrict__ A, const unsigned short* __restrict__ Bw,
    const float* __restrict__ bias, const float* __restrict__ rope,
    unsigned short* __restrict__ Cb, float* __restrict__ outp) {
  constexpr int K = 768;
  constexpr int NK = K / 64;             // 12 K64-tiles
  __shared__ alignas(16) unsigned short lds[65536];   // 128 KiB

  // bijective XCD swizzle
  constexpr int nwg = 260 * NTILES;
  constexpr int q8 = nwg / 8, r8 = nwg % 8;
  int id = blockIdx.x;
  int xcd = id & 7, lid = id >> 3;
  int wg = (xcd < r8 ? xcd * (q8 + 1) : r8 * (q8 + 1) + (xcd - r8) * q8) + lid;
  int mtile = wg / NTILES, ntile = wg - mtile * NTILES;
  int m0 = mtile * 256, n0 = ntile * 256;

  int tid = threadIdx.x;
  int lane = tid & 63, wid = tid >> 6;
  int lq = lane & 15, lg = lane >> 4;
  int wm = (wid >> 2) * 128;             // wave M offset (0 or 128)
  int wn = (wid & 3) * 64;               // wave N offset (0..192)

  // stage one half-tile (16 KB): 2 global_load_lds_dwordx4 per thread.
  // LDS dest linear; global source pre-swizzled chunk = kc ^ (lane>>3).
  int srow0 = wid * 8 + (lane >> 3);     // rows covered: j*64 + srow0
  int skc   = (lane & 7) ^ (lane >> 3);  // swizzled 16B-chunk within 128B row
  auto stage = [&](const unsigned short* G, int off0, int k0, int h, unsigned short* base) {
    #pragma unroll
    for (int j = 0; j < 2; ++j) {
      int row = h * 128 + j * 64 + srow0;
      gload_lds16(G + (size_t)(off0 + row) * K + k0 + skc * 8,
                  base + h * 8192 + (j * 8 + wid) * 512);
    }
  };

  // ds_read of 4 row-fragments x 2 k-slices from a [256][64] swizzled tile
  auto rd8 = [&](bf16x8* dst, const unsigned short* s, int rbase) {
    #pragma unroll
    for (int f = 0; f < 4; ++f)
      #pragma unroll
      for (int ks = 0; ks < 2; ++ks) {
        int row = rbase + f * 16 + lq;
        dst[f * 2 + ks] = *(const bf16x8*)(s + row * 64 + (((ks * 4 + lg) ^ (lq & 7)) * 8));
      }
  };
  auto rd4 = [&](bf16x8* dst, const unsigned short* s, int rbase) {
    #pragma unroll
    for (int f = 0; f < 2; ++f)
      #pragma unroll
      for (int ks = 0; ks < 2; ++ks) {
        int row = rbase + f * 16 + lq;
        dst[f * 2 + ks] = *(const bf16x8*)(s + row * 64 + (((ks * 4 + lg) ^ (lq & 7)) * 8));
      }
  };

  f32x4 acc[8][4];
  #pragma unroll
  for (int i = 0; i < 8; ++i)
    #pragma unroll
    for (int j = 0; j < 4; ++j) acc[i][j] = (f32x4){0.f, 0.f, 0.f, 0.f};

  bf16x8 af[8], b01[4], b23[4];

  #define BARR() __builtin_amdgcn_s_barrier()
  #define LGKM0() do { asm volatile("s_waitcnt lgkmcnt(0)" ::: "memory"); \
                       __builtin_amdgcn_sched_barrier(0); } while (0)

  auto mfma16 = [&](bf16x8* a4, bf16x8* b2, int mb, int nb) {
    __builtin_amdgcn_s_setprio(1);
    #pragma unroll
    for (int mf = 0; mf < 4; ++mf)
      #pragma unroll
      for (int nf = 0; nf < 2; ++nf)
        #pragma unroll
        for (int ks = 0; ks < 2; ++ks)
          acc[mb + mf][nb + nf] =
            __builtin_amdgcn_mfma_f32_16x16x32_bf16(a4[mf * 2 + ks], b2[nf * 2 + ks],
                                                    acc[mb + mf][nb + nf], 0, 0, 0);
    __builtin_amdgcn_s_setprio(0);
  };

  // tile body. stageA: stage A halves of tile T+1 at P0/P1. stageB: B halves of
  // tile T+2 at P2/P3. endcnt: vmcnt at tile boundary (-1 = none).
  auto tile = [&](int T, bool doA, bool doB, int endcnt) {
    const unsigned short* sA = lds + (T & 1) * 16384;
    const unsigned short* sB = lds + 32768 + (T & 1) * 16384;
    unsigned short* dA = lds + ((T + 1) & 1) * 16384;
    unsigned short* dB = lds + 32768 + (T & 1) * 16384;   // (T+2)&1 == T&1

    // P0: A03 + B01 reads; stage A-h0(T+1); MFMA A03xB01
    rd8(af, sA, wm);
    rd4(b01, sB, wn);
    if (doA) stage(A, m0, (T + 1) * 64, 0, dA);
    BARR(); LGKM0();
    mfma16(af, b01, 0, 0);
    BARR();

    // P1: B23 reads; stage A-h1(T+1); MFMA A03xB23
    rd4(b23, sB, wn + 32);
    if (doA) stage(A, m0, (T + 1) * 64, 1, dA);
    BARR(); LGKM0();
    mfma16(af, b23, 0, 2);
    BARR();

    // P2: A47 reads; stage B-h0(T+2); MFMA A47xB23
    rd8(af + 0, sA, wm + 64);
    if (doB) stage(Bw, n0, (T + 2) * 64, 0, dB);
    BARR(); LGKM0();
    mfma16(af, b23, 4, 2);
    BARR();

    // P3: no reads; stage B-h1(T+2); MFMA A47xB01
    if (doB) stage(Bw, n0, (T + 2) * 64, 1, dB);
    BARR();
    mfma16(af, b01, 4, 0);
    if (endcnt == 4) asm volatile("s_waitcnt vmcnt(4)" ::: "memory");
    else if (endcnt == 0) asm volatile("s_waitcnt vmcnt(0)" ::: "memory");
    if (endcnt >= 0) BARR();
  };

  // prologue: tile0 all 4 halves + tile1 B halves (12 loads/wave... 12 instrs,
  // 2/wave per half: per-wave outstanding = 12). vmcnt(4) leaves t1-B in flight.
  {
    unsigned short* a0 = lds;            // buf0 A
    unsigned short* b0 = lds + 32768;    // buf0 B
    unsigned short* b1 = lds + 32768 + 16384;  // buf1 B
    stage(A, m0, 0, 0, a0); stage(A, m0, 0, 1, a0);
    stage(Bw, n0, 0, 0, b0); stage(Bw, n0, 0, 1, b0);
    stage(Bw, n0, 64, 0, b1); stage(Bw, n0, 64, 1, b1);
    asm volatile("s_waitcnt vmcnt(4)" ::: "memory");
    BARR();
  }

  #pragma unroll 2
  for (int T = 0; T < NK - 2; ++T)       // T = 0..9: full stages, vmcnt(4)
    tile(T, true, true, 4);
  tile(NK - 2, true, false, 0);          // T = 10: stage t11 A only, drain
  tile(NK - 1, false, false, -1);        // T = 11: compute only

  #undef BARR
  #undef LGKM0

  // ---- epilogue ----
  #pragma unroll
  for (int mf = 0; mf < 8; ++mf) {
    #pragma unroll
    for (int r = 0; r < 4; ++r) {
      int row = m0 + wm + mf * 16 + (lg << 2) + r;
      int w = row / NT, t = row - w * NT;
      int wy = (w >> 3) & 7, wx = w & 7;
      int py = (wy << 3) + (t >> 3), px = (wx << 3) + (t & 7);
      #pragma unroll
      for (int a = 0; a < 2; ++a) {
        int col0 = n0 + wn + a * 32 + lq;
        int col1 = col0 + 16;
        float v0 = acc[mf][2 * a][r] + bias[col0];
        float v1 = acc[mf][2 * a + 1][r] + bias[col1];
        if (MODE == 0) {
          if (col0 < 1536 && t != 64) {
            int p = a ? px : py;                 // (col0 & 63) >> 5 == a
            const float* rp = rope + ((p << 4) + lq) * 2;
            float cc = rp[0], ss = rp[1];
            float o0 = v0 * cc - v1 * ss;
            float o1 = v1 * cc + v0 * ss;
            v0 = o0; v1 = o1;
          }
          unsigned short* cr = Cb + (size_t)row * C3;
          cr[col0] = f2bf(v0);
          cr[col1] = f2bf(v1);
        } else {
          if (t == 64) {
            float* ub = outp + OUT_IMG + (size_t)(w >> 6) * Cdim;
            atomicAdd(ub + col0, v0 * (1.f / 64.f));
            atomicAdd(ub + col1, v1 * (1.f / 64.f));
          } else {
            float* orow = outp + ((size_t)(w >> 6) * 4096 + py * 64 + px) * Cdim;
            orow[col0] = v0;
            orow[col1] = v1;
          }
        }
      }
    }
  }
}

// ---------- K3: V transpose per (window, head) ----------
__global__ void k_vt(const unsigned short* __restrict__ qkv, unsigned short* __restrict__ Vt) {
  int bh = blockIdx.x;
  int w = bh / 12, h = bh - w * 12;
  __shared__ float sv[65][65];
  const unsigned short* base = qkv + (size_t)w * NT * C3 + 1536 + h * 64;
  for (int i = threadIdx.x; i < 65 * 64; i += 256) {
    int t = i >> 6, d = i & 63;
    sv[t][d] = bf2f(base[(size_t)t * C3 + d]);
  }
  __syncthreads();
  unsigned short* out = Vt + (size_t)bh * 64 * TP;
  for (int i = threadIdx.x; i < 64 * TP; i += 256) {
    int d = i / TP, t = i - d * TP;
    out[i] = f2bf(t < 65 ? sv[t][d] : 0.f);
  }
}

// ---------- K4: attention, 1 wave per (window, head) ----------
__global__ __launch_bounds__(64) void k_attn(const unsigned short* __restrict__ qkv,
                                             const unsigned short* __restrict__ Vt,
                                             unsigned short* __restrict__ att) {
  __shared__ alignas(16) unsigned short P[80 * PS];
  int h = blockIdx.x, w = blockIdx.y;
  int lane = threadIdx.x;
  int lq = lane & 15, lg = lane >> 4;

  const unsigned short* qb = qkv + (size_t)w * NT * C3 + h * 64;
  const unsigned short* kb = qb + 768;

  bf16x8 kf[5][2];
  #pragma unroll
  for (int kt = 0; kt < 5; ++kt)
    #pragma unroll
    for (int ks = 0; ks < 2; ++ks)
      kf[kt][ks] = *(const bf16x8*)(kb + (size_t)(kt * 16 + lq) * C3 + ks * 32 + lg * 8);

  const unsigned short* vb = Vt + (size_t)(w * 12 + h) * 64 * TP;
  bf16x8 vf[3][4];
  #pragma unroll
  for (int ks = 0; ks < 3; ++ks)
    #pragma unroll
    for (int dt = 0; dt < 4; ++dt)
      vf[ks][dt] = *(const bf16x8*)(vb + (size_t)(dt * 16 + lq) * TP + ks * 32 + lg * 8);

  for (int i = lane; i < 80 * 8; i += 64) {
    int row = i >> 3, j = i & 7;
    int byteo = row * (PS * 2) + 160 + j * 4;
    byteo ^= (row & 7) << 4;
    *(unsigned int*)((char*)P + byteo) = 0u;
  }

  #pragma unroll 1
  for (int qt = 0; qt < 5; ++qt) {
    bf16x8 qf[2];
    #pragma unroll
    for (int ks = 0; ks < 2; ++ks)
      qf[ks] = *(const bf16x8*)(qb + (size_t)(qt * 16 + lq) * C3 + ks * 32 + lg * 8);

    f32x4 sa[5];
    #pragma unroll
    for (int kt = 0; kt < 5; ++kt) {
      sa[kt] = (f32x4){0.f, 0.f, 0.f, 0.f};
      #pragma unroll
      for (int ks = 0; ks < 2; ++ks)
        sa[kt] = __builtin_amdgcn_mfma_f32_16x16x32_bf16(kf[kt][ks], qf[ks], sa[kt], 0, 0, 0);
    }
    float pv[5][4];
    float m = -1e30f;
    #pragma unroll
    for (int kt = 0; kt < 5; ++kt)
      #pragma unroll
      for (int r = 0; r < 4; ++r) {
        int tok = kt * 16 + lg * 4 + r;
        float s = sa[kt][r] * 0.125f;
        bool ok = tok < 65;
        pv[kt][r] = ok ? s : -1e30f;
        m = (ok && s > m) ? s : m;
      }
    m = fmaxf(m, __shfl_xor(m, 16));
    m = fmaxf(m, __shfl_xor(m, 32));
    float sum = 0.f;
    #pragma unroll
    for (int kt = 0; kt < 5; ++kt)
      #pragma unroll
      for (int r = 0; r < 4; ++r) {
        float e = (pv[kt][r] > -1e29f) ? exp2f((pv[kt][r] - m) * 1.44269504f) : 0.f;
        pv[kt][r] = e;
        sum += e;
      }
    sum += __shfl_xor(sum, 16);
    sum += __shfl_xor(sum, 32);
    float rinv = 1.f / sum;

    int q = qt * 16 + lq;
    #pragma unroll
    for (int kt = 0; kt < 5; ++kt) {
      unsigned int u0 = (unsigned)f2bf(pv[kt][0] * rinv) | ((unsigned)f2bf(pv[kt][1] * rinv) << 16);
      unsigned int u1 = (unsigned)f2bf(pv[kt][2] * rinv) | ((unsigned)f2bf(pv[kt][3] * rinv) << 16);
      int byteo = q * (PS * 2) + kt * 32 + lg * 8;
      byteo ^= (q & 7) << 4;
      *(u32x2*)((char*)P + byteo) = (u32x2){u0, u1};
    }
    asm volatile("s_waitcnt lgkmcnt(0)" ::: "memory");

    bf16x8 bp[3];
    #pragma unroll
    for (int ks = 0; ks < 3; ++ks) {
      int byteo = q * (PS * 2) + ks * 64 + lg * 16;
      byteo ^= (q & 7) << 4;
      bp[ks] = *(const bf16x8*)((char*)P + byteo);
    }
    #pragma unroll
    for (int dt = 0; dt < 4; ++dt) {
      f32x4 o = (f32x4){0.f, 0.f, 0.f, 0.f};
      #pragma unroll
      for (int ks = 0; ks < 3; ++ks)
        o = __builtin_amdgcn_mfma_f32_16x16x32_bf16(vf[ks][dt], bp[ks], o, 0, 0, 0);
      if (q < 65) {
        unsigned int u0 = (unsigned)f2bf(o[0]) | ((unsigned)f2bf(o[1]) << 16);
        unsigned int u1 = (unsigned)f2bf(o[2]) | ((unsigned)f2bf(o[3]) << 16);
        *(u32x2*)(att + (size_t)(w * NT + q) * Cdim + h * 64 + dt * 16 + lg * 4) = (u32x2){u0, u1};
      }
    }
  }
}

// ---------- host ----------
extern "C" void kernel_launch(void* const* d_in, const int* in_sizes, int n_in,
                              void* d_out, int out_size, void* d_ws, size_t ws_size,
                              hipStream_t stream) {
  const float* x_img  = (const float*)d_in[0];
  const float* unseen = (const float*)d_in[2];
  const float* qkv_w  = (const float*)d_in[3];
  const float* qkv_b  = (const float*)d_in[4];
  const float* proj_w = (const float*)d_in[5];
  const float* proj_b = (const float*)d_in[6];

  char* ws = (char*)d_ws;
  size_t off = 0;
  auto alloc = [&](size_t bytes) { void* p = ws + off; off = (off + bytes + 255) & ~(size_t)255; return p; };
  unsigned short* xw  = (unsigned short*)alloc((size_t)ROWS * Cdim * 2);
  unsigned short* qkv = (unsigned short*)alloc((size_t)ROWS_PAD * C3 * 2);
  unsigned short* Vt  = (unsigned short*)alloc((size_t)12288 * 64 * TP * 2);
  unsigned short* wqb = (unsigned short*)alloc((size_t)C3 * Cdim * 2);
  unsigned short* wpb = (unsigned short*)alloc((size_t)Cdim * Cdim * 2);
  float* rope = (float*)alloc(64 * 16 * 2 * sizeof(float));

  hipMemsetAsync((float*)d_out + OUT_IMG, 0, 16 * Cdim * sizeof(float), stream);

  k_prep<<<512, 256, 0, stream>>>(qkv_w, proj_w, wqb, wpb, rope);
  k_xw<<<ROWS, 192, 0, stream>>>(x_img, unseen, xw);
  k_gemm<0, 9><<<260 * 9, 512, 0, stream>>>(xw, wqb, qkv_b, rope, qkv, nullptr);
  k_vt<<<12288, 256, 0, stream>>>(qkv, Vt);
  k_attn<<<dim3(12, 1024), 64, 0, stream>>>(qkv, Vt, xw);
  k_gemm<1, 3><<<260 * 3, 512, 0, stream>>>(xw, wpb, proj_b, nullptr, nullptr, (float*)d_out);
}